// Round 6
// baseline (387.196 us; speedup 1.0000x reference)
//
#include <hip/hip_runtime.h>
#include <math.h>

#define HW   56
#define DIMC 256
#define HID  1024

typedef __attribute__((ext_vector_type(8))) short bf16x8;
typedef __attribute__((ext_vector_type(4))) float f32x4;

__device__ __forceinline__ short f2bf(float f) {
  union { float fv; unsigned u; } v; v.fv = f;
  unsigned r = v.u + 0x7fffu + ((v.u >> 16) & 1u);
  return (short)(r >> 16);
}
__device__ __forceinline__ float bf2f(short s) {
  union { unsigned u; float fv; } v; v.u = ((unsigned)(unsigned short)s) << 16;
  return v.fv;
}
// gelu via sigmoid: v*sigmoid(1.702v). rcp (1-ulp approx) fine: error scaled
// by gamma=1e-6 before reaching the output.
__device__ __forceinline__ float gelu_fast(float v) {
  float e = exp2f(-2.4556260f * v);
  return v * __builtin_amdgcn_rcpf(1.f + e);
}
// pack 8 f32 -> 8 OCP e4m3 bytes in one i64 (byte j = value j; A and B use the
// same j-indexing so any HW k-permutation within the 8-group cancels in MFMA).
__device__ __forceinline__ long pk8(float f0, float f1, float f2, float f3,
                                    float f4, float f5, float f6, float f7) {
  int lo = __builtin_amdgcn_cvt_pk_fp8_f32(f0, f1, 0, false);
  lo = __builtin_amdgcn_cvt_pk_fp8_f32(f2, f3, lo, true);
  int hi = __builtin_amdgcn_cvt_pk_fp8_f32(f4, f5, 0, false);
  hi = __builtin_amdgcn_cvt_pk_fp8_f32(f6, f7, hi, true);
  return ((long)(unsigned)lo) | ((long)hi << 32);
}
__device__ __forceinline__ char f2fp8(float f) {
  return (char)(__builtin_amdgcn_cvt_pk_fp8_f32(f, f, 0, false) & 0xff);
}

// ---------------------------------------------------------------------------
// prep_pack: weights -> fp8 MFMA-fragment-major (frag = 64 lanes x 8B = 512B).
//  w1p frag (ch*2+nf)*8+k8 : n=ch*32+nf*16+l15, k=k8*32+q*8+j, elem w1[k][n]
//  w2p frag ch*16+cf       : k=ch*32+q*8+j, c=cf*16+l15,       elem w2[k][c]
// ---------------------------------------------------------------------------
__global__ void prep_pack(const float* __restrict__ w1, const float* __restrict__ w2,
                          long* __restrict__ w1p, long* __restrict__ w2p,
                          int* __restrict__ qmeta) {
  int g = blockIdx.x * 256 + threadIdx.x;
  if (g == 0) { qmeta[0] = 0; qmeta[1] = 0; qmeta[2] = 0; }
  int f = g >> 6, lane = g & 63;
  int l15 = lane & 15, q = lane >> 4;
  float t[8];
  if (f < 512) {
    int k8 = f & 7, tt = f >> 3, nt = tt & 1, ch = tt >> 1;
    int n = ch * 32 + nt * 16 + l15;
    int k = k8 * 32 + q * 8;
    #pragma unroll
    for (int j = 0; j < 8; ++j) t[j] = w1[(k + j) * HID + n];
    w1p[f * 64 + lane] = pk8(t[0], t[1], t[2], t[3], t[4], t[5], t[6], t[7]);
  } else {
    int f2 = f - 512;
    int nt2 = f2 & 15, ch = f2 >> 4;
    int k = ch * 32 + q * 8;
    int c = nt2 * 16 + l15;
    #pragma unroll
    for (int j = 0; j < 8; ++j) t[j] = w2[(k + j) * DIMC + c];
    w2p[f2 * 64 + lane] = pk8(t[0], t[1], t[2], t[3], t[4], t[5], t[6], t[7]);
  }
}

// ---------------------------------------------------------------------------
// compact_k: dense active-tile list. qmeta[0]=count, [1]=mlp head, list at +16.
// ---------------------------------------------------------------------------
__global__ void compact_k(const int* __restrict__ mask, int* __restrict__ qmeta) {
  int t = blockIdx.x * 256 + threadIdx.x;
  if (t < 1568 && mask[t]) {
    int i = atomicAdd(qmeta, 1);
    qmeta[16 + i] = t;
  }
}

// ---------------------------------------------------------------------------
// conv_k v4 (unchanged, proven): DENSE per-(b,c) plane, x read exactly once,
// rolling 7-row register window, weights in SGPRs, per-row mask skip.
// ---------------------------------------------------------------------------
__global__ __launch_bounds__(256, 4) void conv_k(
    const float* __restrict__ x, const int* __restrict__ mask,
    const float* __restrict__ dw_w, const float* __restrict__ dw_b,
    short* __restrict__ ybuf) {
  __shared__ __align__(16) float s_plane[62 * 64];        // 15872 B
  __shared__ __align__(16) short s_out[56 * 64];          // 7168 B

  int bid = blockIdx.x;
  int c = bid & 255, b = bid >> 8;
  int tid = threadIdx.x;
  const float* xp = x + (long)(b * DIMC + c) * HW * HW;

  #pragma unroll
  for (int it = 0; it < 4; ++it) {
    int slot = tid + 256 * it;
    if (slot < 992) {
      int row = slot >> 4, jj = slot & 15;
      f32x4 v = (f32x4){0.f, 0.f, 0.f, 0.f};
      if (row >= 3 && row < 59 && jj >= 1 && jj <= 14)
        v = *(const f32x4*)(xp + (row - 3) * HW + (jj * 4 - 4));
      *(f32x4*)(s_plane + row * 64 + jj * 4) = v;
    }
  }

  float wt[49];
  #pragma unroll
  for (int j = 0; j < 49; ++j) {
    int wi = __builtin_amdgcn_readfirstlane(__builtin_bit_cast(int, dw_w[c * 49 + j]));
    wt[j] = __builtin_bit_cast(float, wi);
  }
  float db = dw_b[c];
  __syncthreads();

  int cp = tid & 31, rg = tid >> 5;             // col-pair, row-group (7 rows)
  if (cp < 28) {
    int col0 = cp * 2, wb = col0 >> 3;
    int r0 = rg * 7;
    int mrow = 0;
    #pragma unroll
    for (int hb = 0; hb < 7; ++hb)
      mrow |= (mask[(b * 7 + hb) * 7 + wb] ? 1 : 0) << hb;
    int hb1 = r0 >> 3, hb2 = (r0 + 6) >> 3;
    if (mrow & ((2 << hb2) - (1 << hb1))) {
      float W[7][10];
#define LDROW(S, LR) do { int _o = (LR) * 64 + col0;                         \
      W[S][0] = s_plane[_o + 0]; W[S][1] = s_plane[_o + 1];                  \
      W[S][2] = s_plane[_o + 2]; W[S][3] = s_plane[_o + 3];                  \
      W[S][4] = s_plane[_o + 4]; W[S][5] = s_plane[_o + 5];                  \
      W[S][6] = s_plane[_o + 6]; W[S][7] = s_plane[_o + 7];                  \
      W[S][8] = s_plane[_o + 8]; W[S][9] = s_plane[_o + 9]; } while (0)
      LDROW(0, r0 + 0); LDROW(1, r0 + 1); LDROW(2, r0 + 2);
      LDROW(3, r0 + 3); LDROW(4, r0 + 4); LDROW(5, r0 + 5);
      #pragma unroll
      for (int k = 0; k < 7; ++k) {
        LDROW((6 + k) % 7, r0 + 6 + k);
        int r = r0 + k;
        if ((mrow >> (r >> 3)) & 1) {
          float out0 = 0.f, out1 = 0.f;
          #pragma unroll
          for (int dy = 0; dy < 7; ++dy) {
            const float* wr = wt + dy * 7;
            const float* ww = W[(k + dy) % 7];
            #pragma unroll
            for (int dx = 0; dx < 7; ++dx) {
              out0 += wr[dx] * ww[1 + dx];
              out1 += wr[dx] * ww[2 + dx];
            }
          }
          unsigned pk = (unsigned)(unsigned short)f2bf(out0 + db)
                      | ((unsigned)(unsigned short)f2bf(out1 + db) << 16);
          ((int*)s_out)[r * 32 + cp] = (int)pk;
        }
      }
#undef LDROW
    }
  }
  __syncthreads();

  #pragma unroll
  for (int it = 0; it < 2; ++it) {
    int u = tid + 256 * it;
    if (u < 392) {
      int hh = u & 7, th = u >> 3;
      int hbL = th / 7, wbL = th % 7;
      int tile = (b * 7 + hbL) * 7 + wbL;
      if (mask[tile]) {
        bf16x8 v = *(const bf16x8*)(s_out + (hbL * 8 + hh) * 64 + wbL * 8);
        *(bf16x8*)(ybuf + ((long)tile * DIMC + c) * 64 + hh * 8) = v;
      }
    }
  }
}

// ---------------------------------------------------------------------------
// mlp_k v7: BARRIER-FREE chunk loop. 128-thread blocks (2 waves), wave owns 32
// positions end-to-end: GEMM1 (2Mx2N frags, all 32 hidden) -> gelu -> h in a
// wave-PRIVATE LDS patch [32][40] fp8 (same-wave write->read = no barrier) ->
// GEMM2 accumulates all 256 c for its rows (z = 128 VGPRs). R5 counters showed
// chunk period 2430cyc vs ~600 busy => 65% barrier/latency idle; this removes
// all 32 per-chunk __syncthreads and gives 8 independent waves/CU (4 blocks).
// LDS 39424B: [0,16384) scratch(staging 16p phases)/s_del(2x8192 per-wave
// fp8 delta) | 16384 h 2x1280 | 18944 s_a8 [64][264] fp8 | 35840 stats/ln.
// ---------------------------------------------------------------------------
__global__ __launch_bounds__(128, 2) void mlp_k(
    const float* __restrict__ ln_w, const float* __restrict__ ln_b,
    const float* __restrict__ b1v, const float* __restrict__ b2v,
    const long* __restrict__ w1p, const long* __restrict__ w2p,
    int* __restrict__ qmeta, short* __restrict__ ybuf) {
  __shared__ __align__(16) char smem[39424];
  __shared__ int s_u;
  short* s_sc  = (short*)smem;                  // staging scratch [16][264] bf16
  char*  s_del = smem;                          // alias: 2 x [256 c][32 p] fp8
  char*  s_h   = smem + 16384;                  // 2 x [32 m][40 k] fp8
  char*  s_a8  = smem + 18944;                  // [p 64][264] fp8 (LN'd A)
  float* s_p1  = (float*)(smem + 35840);        // [8][16]
  float* s_p2  = (float*)(smem + 36352);
  float* s_mu  = (float*)(smem + 36864);        // [64]
  float* s_rs  = (float*)(smem + 37120);
  float* s_lnw = (float*)(smem + 37376);
  float* s_lnb = (float*)(smem + 38400);

  const int* list = qmeta + 16;
  int tid = threadIdx.x;
  int total = qmeta[0];

  s_lnw[tid] = ln_w[tid];       s_lnb[tid] = ln_b[tid];
  s_lnw[tid + 128] = ln_w[tid + 128]; s_lnb[tid + 128] = ln_b[tid + 128];

  const int wv = tid >> 6, lane = tid & 63;
  const int l15 = lane & 15, q = lane >> 4;
  const int r0 = wv * 32;                       // wave's 32 positions

  for (;;) {
    if (tid == 0) s_u = atomicAdd(qmeta + 1, 1);
    __syncthreads();
    int i = s_u;
    if (i >= total) break;
    int tile = list[i];
    const short* ytile = ybuf + (long)tile * DIMC * 64;

    // ---- staging + LN in 4 phases of 16 positions (scratch 8448B) ----
    for (int ph = 0; ph < 4; ++ph) {
      #pragma unroll
      for (int it = 0; it < 4; ++it) {
        int slot = tid + 128 * it;              // 512 = 256c x 2 pd
        int c = slot & 255, pd = slot >> 8;
        bf16x8 v = *(const bf16x8*)(ytile + c * 64 + ph * 16 + pd * 8);
        #pragma unroll
        for (int j = 0; j < 8; ++j) s_sc[(pd * 8 + j) * 264 + c] = v[j];
      }
      __syncthreads();
      int p = tid & 15, cq = tid >> 4;          // cq 0..7 -> 32 c each
      bf16x8 va[4];
      float s1 = 0.f, s2 = 0.f;
      #pragma unroll
      for (int ii = 0; ii < 4; ++ii) {
        va[ii] = *(const bf16x8*)(s_sc + p * 264 + cq * 32 + ii * 8);
        #pragma unroll
        for (int j = 0; j < 8; ++j) { float f = bf2f(va[ii][j]); s1 += f; s2 += f * f; }
      }
      s_p1[cq * 16 + p] = s1; s_p2[cq * 16 + p] = s2;
      __syncthreads();
      if (tid < 16) {
        float t1 = 0.f, t2 = 0.f;
        #pragma unroll
        for (int cqq = 0; cqq < 8; ++cqq) { t1 += s_p1[cqq * 16 + tid]; t2 += s_p2[cqq * 16 + tid]; }
        float mu = t1 * (1.f / 256.f);
        float var = t2 * (1.f / 256.f) - mu * mu;
        s_mu[ph * 16 + tid] = mu; s_rs[ph * 16 + tid] = rsqrtf(var + 1e-6f);
      }
      __syncthreads();
      float mu = s_mu[ph * 16 + p], rs = s_rs[ph * 16 + p];
      #pragma unroll
      for (int ii = 0; ii < 4; ++ii) {
        int c0 = cq * 32 + ii * 8;
        float f[8];
        #pragma unroll
        for (int j = 0; j < 8; ++j)
          f[j] = (bf2f(va[ii][j]) - mu) * rs * s_lnw[c0 + j] + s_lnb[c0 + j];
        *(long*)(s_a8 + (ph * 16 + p) * 264 + c0) = pk8(f[0], f[1], f[2], f[3], f[4], f[5], f[6], f[7]);
      }
    }
    __syncthreads();                            // s_a8 complete (both waves)

    // ---- barrier-free chunk loop ----
    const char* aB0 = s_a8 + (r0 + l15) * 264 + q * 8;
    const char* aB1 = aB0 + 16 * 264;
    char* hw = s_h + wv * 1280;                 // private [32][40]

    f32x4 z[2][16];
    #pragma unroll
    for (int mf = 0; mf < 2; ++mf)
      #pragma unroll
      for (int cf = 0; cf < 16; ++cf) z[mf][cf] = (f32x4){0.f, 0.f, 0.f, 0.f};

    for (int ch = 0; ch < 32; ++ch) {
      long w1f0[8], w1f1[8], w2f[16];           // issue all weight loads first
      #pragma unroll
      for (int k8 = 0; k8 < 8; ++k8) {
        w1f0[k8] = w1p[(long)((ch * 2 + 0) * 8 + k8) * 64 + lane];
        w1f1[k8] = w1p[(long)((ch * 2 + 1) * 8 + k8) * 64 + lane];
      }
      #pragma unroll
      for (int cf = 0; cf < 16; ++cf)
        w2f[cf] = w2p[(long)(ch * 16 + cf) * 64 + lane];
      float bb0 = b1v[ch * 32 + l15];
      float bb1 = b1v[ch * 32 + 16 + l15];

      f32x4 a00 = (f32x4){0.f,0.f,0.f,0.f}, a01 = (f32x4){0.f,0.f,0.f,0.f};
      f32x4 a10 = (f32x4){0.f,0.f,0.f,0.f}, a11 = (f32x4){0.f,0.f,0.f,0.f};
      __builtin_amdgcn_s_setprio(1);
      #pragma unroll
      for (int k8 = 0; k8 < 8; ++k8) {
        long a0 = *(const long*)(aB0 + k8 * 32);
        long a1 = *(const long*)(aB1 + k8 * 32);
        a00 = __builtin_amdgcn_mfma_f32_16x16x32_fp8_fp8(a0, w1f0[k8], a00, 0, 0, 0);
        a01 = __builtin_amdgcn_mfma_f32_16x16x32_fp8_fp8(a0, w1f1[k8], a01, 0, 0, 0);
        a10 = __builtin_amdgcn_mfma_f32_16x16x32_fp8_fp8(a1, w1f0[k8], a10, 0, 0, 0);
        a11 = __builtin_amdgcn_mfma_f32_16x16x32_fp8_fp8(a1, w1f1[k8], a11, 0, 0, 0);
      }
      __builtin_amdgcn_s_setprio(0);
      // gelu -> private h patch [m][k]: m = mf*16+q*4+r, k = nf*16+l15
      #pragma unroll
      for (int r = 0; r < 4; ++r) {
        hw[(q * 4 + r) * 40 + l15]           = f2fp8(gelu_fast(a00[r] + bb0));
        hw[(q * 4 + r) * 40 + 16 + l15]      = f2fp8(gelu_fast(a01[r] + bb1));
        hw[(16 + q * 4 + r) * 40 + l15]      = f2fp8(gelu_fast(a10[r] + bb0));
        hw[(16 + q * 4 + r) * 40 + 16 + l15] = f2fp8(gelu_fast(a11[r] + bb1));
      }
      long aH0 = *(const long*)(hw + l15 * 40 + q * 8);        // lgkm auto-wait
      long aH1 = *(const long*)(hw + (16 + l15) * 40 + q * 8);
      __builtin_amdgcn_s_setprio(1);
      #pragma unroll
      for (int cf = 0; cf < 16; ++cf) {
        z[0][cf] = __builtin_amdgcn_mfma_f32_16x16x32_fp8_fp8(aH0, w2f[cf], z[0][cf], 0, 0, 0);
        z[1][cf] = __builtin_amdgcn_mfma_f32_16x16x32_fp8_fp8(aH1, w2f[cf], z[1][cf], 0, 0, 0);
      }
      __builtin_amdgcn_s_setprio(0);
    }

    // ---- epilogue (wave-private, no barrier): z+b2 -> fp8 delta slice ----
    char* sd = s_del + wv * 8192;               // [256 c][32 p]
    #pragma unroll
    for (int cf = 0; cf < 16; ++cf) {
      int c = cf * 16 + l15;
      float bb = b2v[c];
      #pragma unroll
      for (int mf = 0; mf < 2; ++mf)
        #pragma unroll
        for (int r = 0; r < 4; ++r)
          sd[c * 32 + mf * 16 + q * 4 + r] = f2fp8(z[mf][cf][r] + bb);
    }
    char* dtile8 = (char*)(ybuf + (long)tile * DIMC * 64);
    #pragma unroll
    for (int it = 0; it < 16; ++it) {
      int u = lane + 64 * it;                   // 1024 = 256c x 4 longs
      int c = u >> 2, pd = (u & 3) * 8;
      *(long*)(dtile8 + c * 64 + r0 + pd) = *(const long*)(sd + c * 32 + pd);
    }
    // top-of-loop __syncthreads covers scratch/s_a8 reuse for the next tile
  }
}

// ---------------------------------------------------------------------------
// epi_k: dense, fully coalesced. out = x + (active ? gamma_c * fp8(delta) : 0).
// ---------------------------------------------------------------------------
__global__ __launch_bounds__(256) void epi_k(
    const float* __restrict__ x, const int* __restrict__ mask,
    const short* __restrict__ delta, const float* __restrict__ gammav,
    float* __restrict__ out) {
  const char* delta8 = (const char*)delta;
  const int NU = 32 * DIMC * HW * 7;            // units of 8 floats
  int stride = gridDim.x * 256;
  for (int u = blockIdx.x * 256 + threadIdx.x; u < NU; u += stride) {
    int wb = u % 7; int t1 = u / 7;
    int h = t1 % 56; int t2 = t1 / 56;
    int c = t2 & 255; int b = t2 >> 8;
    int g = ((b * DIMC + c) * HW + h) * HW + wb * 8;
    f32x4 x0 = *(const f32x4*)(x + g);
    f32x4 x1 = *(const f32x4*)(x + g + 4);
    int tile = (b * 7 + (h >> 3)) * 7 + wb;
    if (mask[tile]) {
      long dl = *(const long*)(delta8 + (long)tile * 32768 + c * 64 + (h & 7) * 8);
      int lo = (int)(unsigned)dl, hi = (int)((unsigned long)dl >> 32);
      float gm = gammav[c];
      x0[0] += gm * __builtin_amdgcn_cvt_f32_fp8(lo, 0);
      x0[1] += gm * __builtin_amdgcn_cvt_f32_fp8(lo, 1);
      x0[2] += gm * __builtin_amdgcn_cvt_f32_fp8(lo, 2);
      x0[3] += gm * __builtin_amdgcn_cvt_f32_fp8(lo, 3);
      x1[0] += gm * __builtin_amdgcn_cvt_f32_fp8(hi, 0);
      x1[1] += gm * __builtin_amdgcn_cvt_f32_fp8(hi, 1);
      x1[2] += gm * __builtin_amdgcn_cvt_f32_fp8(hi, 2);
      x1[3] += gm * __builtin_amdgcn_cvt_f32_fp8(hi, 3);
    }
    *(f32x4*)(out + g) = x0;
    *(f32x4*)(out + g + 4) = x1;
  }
}

extern "C" void kernel_launch(void* const* d_in, const int* in_sizes, int n_in,
                              void* d_out, int out_size, void* d_ws, size_t ws_size,
                              hipStream_t stream) {
  const float* x    = (const float*)d_in[0];
  const int*   mask = (const int*)d_in[1];
  const float* dw_w = (const float*)d_in[2];
  const float* dw_b = (const float*)d_in[3];
  const float* ln_w = (const float*)d_in[4];
  const float* ln_b = (const float*)d_in[5];
  const float* w1   = (const float*)d_in[6];
  const float* b1   = (const float*)d_in[7];
  const float* w2   = (const float*)d_in[8];
  const float* b2   = (const float*)d_in[9];
  const float* gm   = (const float*)d_in[10];
  float* out = (float*)d_out;

  long* w1p  = (long*)d_ws;                     // 256 KB (512 frags x 512B)
  long* w2p  = w1p + 512 * 64;                  // 256 KB
  int*  qmeta = (int*)(w2p + 512 * 64);         // 8 KB: counters + tile list
  short* ybuf = (short*)((char*)qmeta + 8192);  // 51.4 MB

  prep_pack<<<256, 256, 0, stream>>>(w1, w2, w1p, w2p, qmeta);
  compact_k<<<7, 256, 0, stream>>>(mask, qmeta);
  conv_k<<<8192, 256, 0, stream>>>(x, mask, dw_w, dw_b, ybuf);
  mlp_k<<<1024, 128, 0, stream>>>(ln_w, ln_b, b1, b2, w1p, w2p, qmeta, ybuf);
  epi_k<<<4096, 256, 0, stream>>>(x, mask, ybuf, gm, out);
}